// Round 8
// baseline (387.143 us; speedup 1.0000x reference)
//
#include <hip/hip_runtime.h>
#include <hip/hip_bf16.h>
#include <math.h>

#define CH 256
#define SCAN_BLOCK 1024

typedef short bf16x8 __attribute__((ext_vector_type(8)));
typedef float f32x4 __attribute__((ext_vector_type(4)));

__device__ __forceinline__ float lrelu(float v) { return fmaxf(v, 0.2f * v); }
__device__ __forceinline__ float elu(float v)   { return v > 0.f ? v : __expf(v) - 1.f; }

__device__ __forceinline__ unsigned short f2bf(float f) {
    unsigned u = __float_as_uint(f);
    return (unsigned short)((u + 0x7fffu + ((u >> 16) & 1u)) >> 16);
}
__device__ __forceinline__ float4 bf4(uint2 u) {
    return make_float4(__uint_as_float(u.x << 16), __uint_as_float(u.x & 0xffff0000u),
                       __uint_as_float(u.y << 16), __uint_as_float(u.y & 0xffff0000u));
}
__device__ __forceinline__ float4 ldbf4(const unsigned short* rowbase, int lane) {
    return bf4(((const uint2*)rowbase)[lane]);
}
__device__ __forceinline__ void stbf4(unsigned short* rowbase, int lane, float4 v) {
    uint2 u;
    u.x = (unsigned)f2bf(v.x) | ((unsigned)f2bf(v.y) << 16);
    u.y = (unsigned)f2bf(v.z) | ((unsigned)f2bf(v.w) << 16);
    ((uint2*)rowbase)[lane] = u;
}

// ---------------- GEMM1: x (n x 20) @ W (20 x 256) + b -> bf16 xl, xr ----------------
__global__ __launch_bounds__(256) void gemm1_kernel(const float* __restrict__ x,
                             const float* __restrict__ Wl, const float* __restrict__ bl,
                             const float* __restrict__ Wr, const float* __restrict__ br,
                             unsigned short* __restrict__ xl, unsigned short* __restrict__ xr, int n) {
    __shared__ float xs[64][20];
    int n0 = blockIdx.x * 64;
    int tid = threadIdx.x;
    for (int i = tid; i < 64 * 20; i += 256) {
        int m = i / 20, k = i % 20;
        int row = n0 + m;
        xs[m][k] = (row < n) ? x[(size_t)row * 20 + k] : 0.f;
    }
    int c = tid;
    float wl[20], wr[20];
#pragma unroll
    for (int k = 0; k < 20; ++k) { wl[k] = Wl[k * 256 + c]; wr[k] = Wr[k * 256 + c]; }
    float blv = bl[c], brv = br[c];
    __syncthreads();
#pragma unroll 1
    for (int g = 0; g < 8; ++g) {
        int base = g * 8;
        float al[8], ar[8];
#pragma unroll
        for (int m = 0; m < 8; ++m) { al[m] = blv; ar[m] = brv; }
#pragma unroll
        for (int k = 0; k < 20; ++k) {
            float wlv = wl[k], wrv = wr[k];
#pragma unroll
            for (int m = 0; m < 8; ++m) {
                float xv = xs[base + m][k];
                al[m] += xv * wlv;
                ar[m] += xv * wrv;
            }
        }
#pragma unroll
        for (int m = 0; m < 8; ++m) {
            int row = n0 + base + m;
            if (row < n) {
                xl[(size_t)row * 256 + c] = f2bf(al[m]);
                xr[(size_t)row * 256 + c] = f2bf(ar[m]);
            }
        }
    }
}

// ---------------- CSR build ----------------
__global__ void count_deg(const int* __restrict__ ei, int* __restrict__ deg, int e) {
    int t = blockIdx.x * blockDim.x + threadIdx.x;
    if (t < e) atomicAdd(&deg[ei[e + t]], 1);
}

__global__ void scan_block_k(const int* __restrict__ deg, int* __restrict__ rowptr,
                             int* __restrict__ bsums, int n) {
    __shared__ int wsum[16];
    __shared__ int woff[17];
    int tid = threadIdx.x;
    int gi = blockIdx.x * SCAN_BLOCK + tid;
    int lane = tid & 63, wid = tid >> 6;
    int v = (gi < n) ? deg[gi] : 0;
    int incl = v;
#pragma unroll
    for (int d = 1; d < 64; d <<= 1) {
        int t = __shfl_up(incl, d, 64);
        if (lane >= d) incl += t;
    }
    if (lane == 63) wsum[wid] = incl;
    __syncthreads();
    if (tid < 16) {
        int s = wsum[tid];
#pragma unroll
        for (int d = 1; d < 16; d <<= 1) {
            int t = __shfl_up(s, d, 64);
            if (tid >= d) s += t;
        }
        woff[tid + 1] = s;
        if (tid == 0) woff[0] = 0;
    }
    __syncthreads();
    incl += woff[wid];
    if (gi < n) rowptr[gi + 1] = incl;
    if (tid == 0) bsums[blockIdx.x] = woff[16];
}

__global__ void scan_tops_k(int* bsums, int nb) {
    int tid = threadIdx.x;
    int v = (tid < nb) ? bsums[tid] : 0;
    int incl = v;
#pragma unroll
    for (int d = 1; d < 64; d <<= 1) {
        int t = __shfl_up(incl, d, 64);
        if (tid >= d) incl += t;
    }
    if (tid < nb) bsums[tid] = incl - v;
}

__global__ void scan_fix_k(int* __restrict__ rowptr, int* __restrict__ cursor,
                           const int* __restrict__ deg, const int* __restrict__ bsums, int n) {
    int gi = blockIdx.x * SCAN_BLOCK + threadIdx.x;
    if (gi >= n) return;
    int off = bsums[blockIdx.x];
    int incl = rowptr[gi + 1] + off;
    rowptr[gi + 1] = incl;
    cursor[gi] = incl - deg[gi];
    if (gi == 0) rowptr[0] = 0;
}

__global__ void scatter_k(const int* __restrict__ ei, int* __restrict__ cursor,
                          int* __restrict__ csr, int e) {
    int t = blockIdx.x * blockDim.x + threadIdx.x;
    if (t >= e) return;
    int s = ei[t], d = ei[e + t];
    int idx = atomicAdd(&cursor[d], 1);
    csr[idx] = s;
}

// ---------------- Fused GATv2 layer 1 (bf16 in, bf16 out) ----------------
// No online-max (softmax shift-invariance; logits are small), 8-edge batches
// with one-batch gather prefetch.
__global__ void fused_gat1(const unsigned short* __restrict__ xl, const unsigned short* __restrict__ xr,
                           const int* __restrict__ rowptr, const int* __restrict__ csr,
                           const float* __restrict__ att, const float* __restrict__ bias,
                           unsigned short* __restrict__ hout, int n) {
    int wid = threadIdx.x >> 6;
    int lane = threadIdx.x & 63;
    int i = blockIdx.x * 4 + wid;
    if (i >= n) return;
    float4 xr4 = ldbf4(xr + (size_t)i * CH, lane);
    float4 a4  = ((const float4*)att)[lane];
    float4 xli = ldbf4(xl + (size_t)i * CH, lane);
    float ps = lrelu(xli.x + xr4.x) * a4.x + lrelu(xli.y + xr4.y) * a4.y +
               lrelu(xli.z + xr4.z) * a4.z + lrelu(xli.w + xr4.w) * a4.w;
    ps += __shfl_xor(ps, 1); ps += __shfl_xor(ps, 2);
    ps += __shfl_xor(ps, 4); ps += __shfl_xor(ps, 8);
    float ws = __expf(ps);
    float l = ws;
    float4 acc = make_float4(ws * xli.x, ws * xli.y, ws * xli.z, ws * xli.w);
    int beg = rowptr[i], end = rowptr[i + 1];

    uint2 raw[8];
#pragma unroll
    for (int j = 0; j < 8; ++j) {
        int s = (beg + j < end) ? csr[beg + j] : i;
        raw[j] = ((const uint2*)(xl + (size_t)s * CH))[lane];
    }
    for (int e = beg; e < end; e += 8) {
        int rem = end - e;
        bool more = (e + 8) < end;
        uint2 raw2[8];
        if (more) {
#pragma unroll
            for (int j = 0; j < 8; ++j) {
                int s = (e + 8 + j < end) ? csr[e + 8 + j] : i;
                raw2[j] = ((const uint2*)(xl + (size_t)s * CH))[lane];
            }
        }
        float4 rr[8];
#pragma unroll
        for (int j = 0; j < 8; ++j) rr[j] = bf4(raw[j]);
        float pp[8];
#pragma unroll
        for (int j = 0; j < 8; ++j)
            pp[j] = lrelu(rr[j].x + xr4.x) * a4.x + lrelu(rr[j].y + xr4.y) * a4.y +
                    lrelu(rr[j].z + xr4.z) * a4.z + lrelu(rr[j].w + xr4.w) * a4.w;
#pragma unroll
        for (int d = 1; d < 16; d <<= 1)
#pragma unroll
            for (int j = 0; j < 8; ++j) pp[j] += __shfl_xor(pp[j], d);
        float ww[8];
#pragma unroll
        for (int j = 0; j < 8; ++j) ww[j] = (j < rem) ? __expf(pp[j]) : 0.f;
#pragma unroll
        for (int j = 0; j < 8; ++j) {
            l += ww[j];
            acc.x += ww[j] * rr[j].x;
            acc.y += ww[j] * rr[j].y;
            acc.z += ww[j] * rr[j].z;
            acc.w += ww[j] * rr[j].w;
        }
        if (more) {
#pragma unroll
            for (int j = 0; j < 8; ++j) raw[j] = raw2[j];
        }
    }
    float inv = 1.f / (l + 1e-16f);
    float4 b4 = ((const float4*)bias)[lane];
    float4 o;
    o.x = elu(acc.x * inv + b4.x);
    o.y = elu(acc.y * inv + b4.y);
    o.z = elu(acc.z * inv + b4.z);
    o.w = elu(acc.w * inv + b4.w);
    stbf4(hout + (size_t)i * CH, lane, o);
}

// ---------------- Fused GATv2 layer 2 (bf16 in, fp32 out) ----------------
__global__ void fused_gat2(const unsigned short* __restrict__ xl, const unsigned short* __restrict__ xr,
                           const int* __restrict__ rowptr, const int* __restrict__ csr,
                           const float* __restrict__ att, const float* __restrict__ bias,
                           float* __restrict__ out, int n) {
    int wid = threadIdx.x >> 6;
    int lane = threadIdx.x & 63;
    int i = blockIdx.x * 4 + wid;
    if (i >= n) return;
    float4 xr4 = ldbf4(xr + (size_t)i * CH, lane);
    float4 a4  = ((const float4*)att)[lane];
    float4 xli = ldbf4(xl + (size_t)i * CH, lane);
    float ps = lrelu(xli.x + xr4.x) * a4.x + lrelu(xli.y + xr4.y) * a4.y +
               lrelu(xli.z + xr4.z) * a4.z + lrelu(xli.w + xr4.w) * a4.w;
    ps += __shfl_xor(ps, 1); ps += __shfl_xor(ps, 2); ps += __shfl_xor(ps, 4);
    ps += __shfl_xor(ps, 8); ps += __shfl_xor(ps, 16); ps += __shfl_xor(ps, 32);
    float ws = __expf(ps);
    float l = ws;
    float4 acc = make_float4(ws * xli.x, ws * xli.y, ws * xli.z, ws * xli.w);
    int beg = rowptr[i], end = rowptr[i + 1];

    uint2 raw[8];
#pragma unroll
    for (int j = 0; j < 8; ++j) {
        int s = (beg + j < end) ? csr[beg + j] : i;
        raw[j] = ((const uint2*)(xl + (size_t)s * CH))[lane];
    }
    for (int e = beg; e < end; e += 8) {
        int rem = end - e;
        bool more = (e + 8) < end;
        uint2 raw2[8];
        if (more) {
#pragma unroll
            for (int j = 0; j < 8; ++j) {
                int s = (e + 8 + j < end) ? csr[e + 8 + j] : i;
                raw2[j] = ((const uint2*)(xl + (size_t)s * CH))[lane];
            }
        }
        float4 rr[8];
#pragma unroll
        for (int j = 0; j < 8; ++j) rr[j] = bf4(raw[j]);
        float pp[8];
#pragma unroll
        for (int j = 0; j < 8; ++j)
            pp[j] = lrelu(rr[j].x + xr4.x) * a4.x + lrelu(rr[j].y + xr4.y) * a4.y +
                    lrelu(rr[j].z + xr4.z) * a4.z + lrelu(rr[j].w + xr4.w) * a4.w;
#pragma unroll
        for (int d = 1; d < 64; d <<= 1)
#pragma unroll
            for (int j = 0; j < 8; ++j) pp[j] += __shfl_xor(pp[j], d);
        float ww[8];
#pragma unroll
        for (int j = 0; j < 8; ++j) ww[j] = (j < rem) ? __expf(pp[j]) : 0.f;
#pragma unroll
        for (int j = 0; j < 8; ++j) {
            l += ww[j];
            acc.x += ww[j] * rr[j].x;
            acc.y += ww[j] * rr[j].y;
            acc.z += ww[j] * rr[j].z;
            acc.w += ww[j] * rr[j].w;
        }
        if (more) {
#pragma unroll
            for (int j = 0; j < 8; ++j) raw[j] = raw2[j];
        }
    }
    float inv = 1.f / (l + 1e-16f);
    float4 b4 = ((const float4*)bias)[lane];
    float4 o;
    o.x = acc.x * inv + b4.x;
    o.y = acc.y * inv + b4.y;
    o.z = acc.z * inv + b4.z;
    o.w = acc.w * inv + b4.w;
    ((float4*)(out + (size_t)i * CH))[lane] = o;
}

// ---------------- transpose+convert layer2 weights: Wt[z][n][k] bf16 ----------------
__global__ void wconv(const float* __restrict__ Wl2, const float* __restrict__ Wr2,
                      unsigned short* __restrict__ Wt) {
    int t = blockIdx.x * 256 + threadIdx.x;
    int z = t >> 16;
    int idx = t & 65535;
    int k = idx >> 8, nn = idx & 255;
    const float* W = z ? Wr2 : Wl2;
    Wt[z * 65536 + nn * 256 + k] = f2bf(W[k * 256 + nn]);
}

// ---------------- GEMM2 MFMA v3 ----------------
#define LDA2 264
#define LDC2 136
__global__ __launch_bounds__(256) void gemm_mfma(
        const unsigned short* __restrict__ A,
        const unsigned short* __restrict__ Wt,   // [z][n][k] bf16
        const float* __restrict__ ba, const float* __restrict__ bb,
        unsigned short* __restrict__ Ca, unsigned short* __restrict__ Cb, int M) {
    int b = blockIdx.x;
    int y = b & 1, mt = b >> 1;
    int m0 = mt * 64, n0 = y * 128;

    __shared__ unsigned short As[64 * LDA2];
    __shared__ unsigned short Cs[64 * LDC2];

    int tid = threadIdx.x, lane = tid & 63, wn = tid >> 6;
    int q = lane >> 4, l15 = lane & 15;

    {
        int row = tid >> 2, quarter = tid & 3;
        bool ok = (m0 + row) < M;
        const uint4* gA = (const uint4*)(A + (size_t)(m0 + row) * 256 + quarter * 64);
        uint4* sA = (uint4*)(As + row * LDA2 + quarter * 64);
        const uint4 z4 = make_uint4(0, 0, 0, 0);
        uint4 v[8];
#pragma unroll
        for (int i = 0; i < 8; ++i) v[i] = ok ? gA[i] : z4;
#pragma unroll
        for (int i = 0; i < 8; ++i) sA[i] = v[i];
    }
    __syncthreads();

    const unsigned short* gB = Wt + (size_t)(n0 + wn * 32 + l15) * 256 + q * 8;

    bf16x8 b_cur[2], b_nxt[2];
#pragma unroll
    for (int j = 0; j < 2; ++j) {
        b_cur[j] = *(const bf16x8*)(gB + j * 16 * 256);
        b_nxt[j] = b_cur[j];
    }

#pragma unroll
    for (int z = 0; z < 2; ++z) {
        f32x4 acc[4][2];
#pragma unroll
        for (int i = 0; i < 4; ++i)
#pragma unroll
            for (int j = 0; j < 2; ++j) acc[i][j] = (f32x4){0.f, 0.f, 0.f, 0.f};

#pragma unroll
        for (int kb = 0; kb < 8; ++kb) {
            if (!(z == 1 && kb == 7)) {
                int zn = (kb == 7) ? 1 : z;
                int kn = (kb == 7) ? 0 : kb + 1;
#pragma unroll
                for (int j = 0; j < 2; ++j)
                    b_nxt[j] = *(const bf16x8*)(gB + (size_t)zn * 65536 + j * 16 * 256 + kn * 32);
            }
            bf16x8 a[4];
#pragma unroll
            for (int i = 0; i < 4; ++i)
                a[i] = *(const bf16x8*)&As[(i * 16 + l15) * LDA2 + kb * 32 + q * 8];
#pragma unroll
            for (int i = 0; i < 4; ++i)
#pragma unroll
                for (int j = 0; j < 2; ++j)
                    acc[i][j] = __builtin_amdgcn_mfma_f32_16x16x32_bf16(a[i], b_cur[j], acc[i][j], 0, 0, 0);
#pragma unroll
            for (int j = 0; j < 2; ++j) b_cur[j] = b_nxt[j];
        }

        const float* bias = z ? bb : ba;
        unsigned short* C = z ? Cb : Ca;
#pragma unroll
        for (int j = 0; j < 2; ++j) {
            int col = wn * 32 + j * 16 + l15;
            float bcol = bias[n0 + col];
#pragma unroll
            for (int i = 0; i < 4; ++i) {
#pragma unroll
                for (int rr = 0; rr < 4; ++rr)
                    Cs[(i * 16 + q * 4 + rr) * LDC2 + col] = f2bf(acc[i][j][rr] + bcol);
            }
        }
        __syncthreads();
        {
            int row = tid >> 2, seg = tid & 3;
            if (m0 + row < M) {
                const uint4* src = (const uint4*)&Cs[row * LDC2 + seg * 32];
                uint4* dst = (uint4*)(C + (size_t)(m0 + row) * 256 + n0 + seg * 32);
#pragma unroll
                for (int i = 0; i < 4; ++i) dst[i] = src[i];
            }
        }
        __syncthreads();
    }
}

extern "C" void kernel_launch(void* const* d_in, const int* in_sizes, int n_in,
                              void* d_out, int out_size, void* d_ws, size_t ws_size,
                              hipStream_t stream) {
    const float* x    = (const float*)d_in[0];
    const int*   ei   = (const int*)d_in[1];
    const float* Wl1  = (const float*)d_in[2];
    const float* bl1  = (const float*)d_in[3];
    const float* Wr1  = (const float*)d_in[4];
    const float* br1  = (const float*)d_in[5];
    const float* att1 = (const float*)d_in[6];
    const float* bias1= (const float*)d_in[7];
    const float* Wl2  = (const float*)d_in[8];
    const float* bl2  = (const float*)d_in[9];
    const float* Wr2  = (const float*)d_in[10];
    const float* br2  = (const float*)d_in[11];
    const float* att2 = (const float*)d_in[12];
    const float* bias2= (const float*)d_in[13];

    int n = in_sizes[0] / 20;
    int e = in_sizes[1] / 2;
    float* out = (float*)d_out;
    size_t nch = (size_t)n * CH;

    unsigned short* buf0 = (unsigned short*)d_ws;
    unsigned short* buf1 = buf0 + nch;
    unsigned short* hbuf = buf1 + nch;
    unsigned short* wt2  = hbuf + nch;
    int* deg    = (int*)(wt2 + 2 * 65536);
    int* rowptr = deg + n;
    int* cursor = rowptr + n + 1;
    int* bsums  = cursor + n;
    int* csr    = bsums + 64;

    hipMemsetAsync(deg, 0, (size_t)n * sizeof(int), stream);

    gemm1_kernel<<<(n + 63) / 64, 256, 0, stream>>>(x, Wl1, bl1, Wr1, br1, buf0, buf1, n);

    count_deg<<<(e + 255) / 256, 256, 0, stream>>>(ei, deg, e);
    int nb = (n + SCAN_BLOCK - 1) / SCAN_BLOCK;
    scan_block_k<<<nb, SCAN_BLOCK, 0, stream>>>(deg, rowptr, bsums, n);
    scan_tops_k<<<1, 64, 0, stream>>>(bsums, nb);
    scan_fix_k<<<nb, SCAN_BLOCK, 0, stream>>>(rowptr, cursor, deg, bsums, n);
    scatter_k<<<(e + 255) / 256, 256, 0, stream>>>(ei, cursor, csr, e);

    wconv<<<512, 256, 0, stream>>>(Wl2, Wr2, wt2);

    fused_gat1<<<(n + 3) / 4, 256, 0, stream>>>(buf0, buf1, rowptr, csr, att1, bias1, hbuf, n);

    gemm_mfma<<<((n + 63) / 64) * 2, 256, 0, stream>>>(hbuf, wt2, bl2, br2, buf0, buf1, n);

    fused_gat2<<<(n + 3) / 4, 256, 0, stream>>>(buf0, buf1, rowptr, csr, att2, bias2, out, n);
}